// Round 1
// baseline (303.939 us; speedup 1.0000x reference)
//
#include <hip/hip_runtime.h>

// ---------------- problem constants ----------------
#define NG      19
#define HEIGHT  256
#define WIDTH   512
#define HW      (HEIGHT*WIDTH)        // 131072
#define BATCH   4
#define TH      16                    // tile rows
#define TW      64                    // tile cols
#define HALO_R  (TH+2)                // 18
#define HALO_C  (TW+2)                // 66
#define LSTRIDE 67                    // odd stride -> 2-way max bank aliasing (free)
#define CH_STRIDE (HALO_R*LSTRIDE)    // 1206
#define LDS_FLOATS (5*CH_STRIDE)      // 6030 floats = 24120 B
#define WXF_FLOATS (NG*720)           // 13680 transformed weights

// Transform W (304,5,3,3) [oc_g=g*16+oc][ic][kr][kc] -> [g][ic][kr][oc][kc]
// so that per-(ic,kr) the 48 weights used by a block are contiguous & uniform.
__global__ void wxform_kernel(const float* __restrict__ W, float* __restrict__ dst) {
    int i = blockIdx.x * 256 + threadIdx.x;
    if (i >= WXF_FLOATS) return;
    int g  = i / 720;  int rem = i % 720;
    int ic = rem / 144; int r2  = rem % 144;
    int kr = r2 / 48;   int r3  = r2 % 48;
    int oc = r3 / 3;    int kc  = r3 % 3;
    dst[i] = W[(((g*16 + oc)*5 + ic)*3 + kr)*3 + kc];
}

__device__ __forceinline__ float fsigmoid(float x) {
    // 1/(1+exp(-x)) ; v_exp_f32 computes 2^x
    return __builtin_amdgcn_rcpf(1.0f + __builtin_amdgcn_exp2f(-1.44269504f * x));
}
__device__ __forceinline__ float ftanh(float x) {
    // tanh(x) = 2*sigmoid(2x) - 1
    return 2.0f * __builtin_amdgcn_rcpf(1.0f + __builtin_amdgcn_exp2f(-2.88539008f * x)) - 1.0f;
}

__launch_bounds__(256, 2)
__global__ void convlstm_kernel(const float* __restrict__ x,
                                const float* __restrict__ h,
                                const float* __restrict__ c,
                                const float* __restrict__ wt,   // transformed weights
                                const float* __restrict__ bias,
                                float* __restrict__ out) {
    __shared__ float lds[LDS_FLOATS];

    const int t    = threadIdx.x;
    const int bid  = blockIdx.x;
    const int bg   = bid >> 7;          // (b*19+g), 128 tiles per image plane
    const int tile = bid & 127;
    const int tr0  = (tile >> 3) * TH;  // 16 row-tiles
    const int tc0  = (tile & 7)  * TW;  // 8 col-tiles
    const int g    = bg % NG;

    // ---- stage 5-channel halo tile (18 x 66) into LDS, zero-padded ----
    const float* xbase = x + bg * HW;
    const float* hbase = h + (bg * 4) * HW;
    const int total = 5 * HALO_R * HALO_C;  // 5940
    for (int f = t; f < total; f += 256) {
        int ch  = f / (HALO_R * HALO_C);
        int rem = f - ch * (HALO_R * HALO_C);
        int r   = rem / HALO_C;
        int cc  = rem - r * HALO_C;
        int gr  = tr0 + r - 1;
        int gc  = tc0 + cc - 1;
        float v = 0.0f;
        if (gr >= 0 && gr < HEIGHT && gc >= 0 && gc < WIDTH) {
            const float* base = (ch == 0) ? xbase : (hbase + (ch - 1) * HW);
            v = base[gr * WIDTH + gc];
        }
        lds[ch * CH_STRIDE + r * LSTRIDE + cc] = v;
    }
    __syncthreads();

    // ---- each thread: 4 consecutive pixels, all 16 group output channels ----
    const int rl = t >> 4;          // 0..15
    const int cl = (t & 15) << 2;   // 0,4,...,60

    const float* wg   = wt + g * 720;
    const float* bp   = bias + g * 16;

    float acc[16][4];
    #pragma unroll
    for (int oc = 0; oc < 16; ++oc) {
        float bv = bp[oc];
        #pragma unroll
        for (int p = 0; p < 4; ++p) acc[oc][p] = bv;
    }

    #pragma unroll
    for (int ic = 0; ic < 5; ++ic) {
        #pragma unroll
        for (int kr = 0; kr < 3; ++kr) {
            const float* lrow = lds + ic * CH_STRIDE + (rl + kr) * LSTRIDE + cl;
            float v0 = lrow[0], v1 = lrow[1], v2 = lrow[2];
            float v3 = lrow[3], v4 = lrow[4], v5 = lrow[5];
            const float* wrow = wg + (ic * 3 + kr) * 48;  // uniform -> s_load
            #pragma unroll
            for (int oc = 0; oc < 16; ++oc) {
                float w0 = wrow[oc*3 + 0];
                float w1 = wrow[oc*3 + 1];
                float w2 = wrow[oc*3 + 2];
                acc[oc][0] = fmaf(v0, w0, fmaf(v1, w1, fmaf(v2, w2, acc[oc][0])));
                acc[oc][1] = fmaf(v1, w0, fmaf(v2, w1, fmaf(v3, w2, acc[oc][1])));
                acc[oc][2] = fmaf(v2, w0, fmaf(v3, w1, fmaf(v4, w2, acc[oc][2])));
                acc[oc][3] = fmaf(v3, w0, fmaf(v4, w1, fmaf(v5, w2, acc[oc][3])));
            }
        }
    }

    // ---- gates + cell update, float4 I/O ----
    const int pixbase = (tr0 + rl) * WIDTH + (tc0 + cl);
    const int NC_OFF  = BATCH * NG * 4 * HW;   // 39,845,888

    #pragma unroll
    for (int s = 0; s < 4; ++s) {
        const int chan = (bg * 4 + s) * HW + pixbase;
        float4 cv = *reinterpret_cast<const float4*>(c + chan);
        float cvx[4] = {cv.x, cv.y, cv.z, cv.w};
        float nhv[4], ncv[4];
        #pragma unroll
        for (int p = 0; p < 4; ++p) {
            float iv = fsigmoid(acc[0*4 + s][p]);
            float fv = fsigmoid(acc[1*4 + s][p]);
            float ov = fsigmoid(acc[2*4 + s][p]);
            float gv = ftanh   (acc[3*4 + s][p]);
            float nc = fv * cvx[p] + iv * gv;
            ncv[p] = nc;
            nhv[p] = ov * ftanh(nc);
        }
        *reinterpret_cast<float4*>(out + chan) =
            make_float4(nhv[0], nhv[1], nhv[2], nhv[3]);
        *reinterpret_cast<float4*>(out + NC_OFF + chan) =
            make_float4(ncv[0], ncv[1], ncv[2], ncv[3]);
    }
}

extern "C" void kernel_launch(void* const* d_in, const int* in_sizes, int n_in,
                              void* d_out, int out_size, void* d_ws, size_t ws_size,
                              hipStream_t stream) {
    (void)in_sizes; (void)n_in; (void)out_size; (void)ws_size;
    const float* x = (const float*)d_in[0];
    const float* h = (const float*)d_in[1];
    const float* c = (const float*)d_in[2];
    const float* W = (const float*)d_in[3];
    const float* b = (const float*)d_in[4];
    float* out = (float*)d_out;
    float* wt  = (float*)d_ws;   // 13680 floats = 54,720 B of scratch

    hipLaunchKernelGGL(wxform_kernel, dim3((WXF_FLOATS + 255) / 256), dim3(256),
                       0, stream, W, wt);
    hipLaunchKernelGGL(convlstm_kernel, dim3(BATCH * NG * 128), dim3(256),
                       0, stream, x, h, c, wt, b, out);
}